// Round 5
// baseline (424.004 us; speedup 1.0000x reference)
//
#include <hip/hip_runtime.h>
#include <math.h>

// Problem constants
#define Bd   4
#define Md   8192
#define Dd   64
#define Sd   1024
#define H0d  32
#define H1d  128

// d_out layout (float offsets), return order:
// sampled_points (B,S,3) | grouped_points (B,S,32,3) | sampled_feature (B,S,64)
// | grouped_feature (B,S,32,64) | Qg (B,S,M)
#define OFF_SP 0
#define OFF_GP 12288
#define OFF_SF 405504
#define OFF_GF 667648          // holds f32 h1 scratch (32768*128 floats = 16MB, region is 32MB)
#define OFF_QG 9056256         // holds f32 logits [B][S][M] until one-hot overwrite

// order-preserving float -> sortable u32
__device__ __forceinline__ unsigned f2u(float f) {
    unsigned v = __float_as_uint(f);
    return (v & 0x80000000u) ? ~v : (v | 0x80000000u);
}

// ---------------------------------------------------------------------------
// K1: per-point MLP (f64 internal math, f32 output).
// coord -> [x,y,z,theta,phi] -> BN/ReLU MLP -> h1[128] (f32, row-major [point][k])
// ---------------------------------------------------------------------------
__global__ __launch_bounds__(256) void k1_mlp(
    const float* __restrict__ coord,
    const float* __restrict__ w0,
    const float* __restrict__ g0, const float* __restrict__ be0,
    const float* __restrict__ mu0, const float* __restrict__ va0,
    const float* __restrict__ w1,
    const float* __restrict__ g1, const float* __restrict__ be1,
    const float* __restrict__ mu1, const float* __restrict__ va1,
    float* __restrict__ h1out)
{
    __shared__ double W1[H0d * H1d];
    __shared__ double W0[5 * H0d];
    __shared__ double MU0[H0d], RS0[H0d], BE0[H0d];
    __shared__ double MU1[H1d], RS1[H1d], BE1[H1d];
    const int t = threadIdx.x;
    for (int i = t; i < H0d * H1d; i += 256) W1[i] = (double)w1[i];
    if (t < 5 * H0d) W0[t] = (double)w0[t];
    if (t < H0d) {
        MU0[t] = (double)mu0[t];
        RS0[t] = (double)g0[t] / sqrt((double)va0[t] + 1e-5);
        BE0[t] = (double)be0[t];
    }
    if (t >= 128) {
        int j = t - 128;
        MU1[j] = (double)mu1[j];
        RS1[j] = (double)g1[j] / sqrt((double)va1[j] + 1e-5);
        BE1[j] = (double)be1[j];
    }
    __syncthreads();

    const int p = blockIdx.x * 256 + t;      // 0..32767  (= b*M + m)
    const double x = (double)coord[p * 3 + 0];
    const double y = (double)coord[p * 3 + 1];
    const double z = (double)coord[p * 3 + 2];
    const double r  = sqrt(x * x + y * y + z * z);
    const double th = acos(z / r);
    const double fi = atan2(y, x);

    double h0[H0d];
    #pragma unroll
    for (int i = 0; i < H0d; i++) {
        double a = x * W0[i] + y * W0[H0d + i] + z * W0[2 * H0d + i]
                 + th * W0[3 * H0d + i] + fi * W0[4 * H0d + i];
        a = (a - MU0[i]) * RS0[i] + BE0[i];
        h0[i] = a > 0.0 ? a : 0.0;
    }
    float* o = h1out + (size_t)p * H1d;
    for (int j = 0; j < H1d; j += 2) {
        double a0 = 0.0, a1 = 0.0;
        #pragma unroll
        for (int i = 0; i < H0d; i++) {
            double h = h0[i];
            a0 += h * W1[i * H1d + j];
            a1 += h * W1[i * H1d + j + 1];
        }
        a0 = (a0 - MU1[j]) * RS1[j] + BE1[j];             a0 = a0 > 0.0 ? a0 : 0.0;
        a1 = (a1 - MU1[j + 1]) * RS1[j + 1] + BE1[j + 1]; a1 = a1 > 0.0 ? a1 : 0.0;
        o[j] = (float)a0; o[j + 1] = (float)a1;
    }
}

// ---------------------------------------------------------------------------
// K2: f32 GEMM.  logits[b][s][m] = sum_k h1[b][m][k] * w2[k][s]
// A staged in LDS [k][m] with XOR swizzle (conflict-free float4 reads);
// w2 tile (32KB) read straight through L1/L2.
// ---------------------------------------------------------------------------
__global__ __launch_bounds__(256) void k2_gemm(
    const float* __restrict__ h1,
    const float* __restrict__ w2,
    float* __restrict__ logits)
{
    __shared__ float As[128 * 64];           // 32 KB, [k][m] XOR-swizzled
    const int bx = blockIdx.x, b = blockIdx.y;
    const int stile = bx & 15, mtile = bx >> 4;
    const int m0 = mtile * 64, s0 = stile * 64;
    const int t = threadIdx.x;

    const float* Ab = h1 + ((size_t)b * Md + m0) * H1d;
    for (int e = t; e < 2048; e += 256) {
        int row = e >> 5;                    // 0..63
        int k4  = e & 31;                    // 0..31
        float4 v = *(const float4*)&Ab[(size_t)row * H1d + k4 * 4];
        #pragma unroll
        for (int j = 0; j < 4; j++) {
            int k = k4 * 4 + j;
            As[k * 64 + ((((row >> 2) ^ (k & 15)) << 2) | (row & 3))] = ((const float*)&v)[j];
        }
    }
    __syncthreads();

    const int mq = t & 15, sq = t >> 4;
    float acc[4][4] = {};
    #pragma unroll 8
    for (int k = 0; k < 128; k++) {
        float4 a  = *(const float4*)&As[k * 64 + ((mq ^ (k & 15)) << 2)];
        float4 bb = *(const float4*)&w2[(size_t)k * Sd + s0 + sq * 4];
        acc[0][0] += bb.x * a.x; acc[0][1] += bb.x * a.y; acc[0][2] += bb.x * a.z; acc[0][3] += bb.x * a.w;
        acc[1][0] += bb.y * a.x; acc[1][1] += bb.y * a.y; acc[1][2] += bb.y * a.z; acc[1][3] += bb.y * a.w;
        acc[2][0] += bb.z * a.x; acc[2][1] += bb.z * a.y; acc[2][2] += bb.z * a.z; acc[2][3] += bb.z * a.w;
        acc[3][0] += bb.w * a.x; acc[3][1] += bb.w * a.y; acc[3][2] += bb.w * a.z; acc[3][3] += bb.w * a.w;
    }
    float* C = logits + ((size_t)b * Sd + s0) * Md + m0;
    #pragma unroll
    for (int si = 0; si < 4; si++) {
        float4 v = make_float4(acc[si][0], acc[si][1], acc[si][2], acc[si][3]);
        *(float4*)&C[(size_t)(sq * 4 + si) * Md + mq * 4] = v;
    }
}

// ---------------------------------------------------------------------------
// K3: per-(b,s) row selection by brute-force iterative extraction.
// Rank domain = f32 Q = sigmoid(logit) (the reference's comparison domain).
// Key = (sortable_u32(Q) << 32) | (8191 - m): u64 max-reduce gives descending
// value with lower-index tie-break, exactly matching jax.lax.top_k.
// Gumbel argmax = same reduce on f32 (Q + g) with first-index tie-break.
// No atomics, fully deterministic.
// ---------------------------------------------------------------------------
__global__ __launch_bounds__(256) void k3_select(
    const float* __restrict__ logits,
    const float* __restrict__ gumbel,
    float* __restrict__ stash)
{
    const int r = blockIdx.x;                // 0..4095
    const int t = threadIdx.x;
    const int lane = t & 63, wav = t >> 6;
    const float* L = logits + (size_t)r * Md;
    const float* G = gumbel + (size_t)r * Md;

    __shared__ unsigned long long wred[2][4];
    __shared__ int order[32];

    unsigned uq[32];
    float    qv[32];
    #pragma unroll
    for (int i = 0; i < 32; i++) {
        float x = L[i * 256 + t];
        float q = 1.0f / (1.0f + expf(-x));
        qv[i] = q;
        uq[i] = f2u(q);                      // Q>0 -> uq >= 0x80000000, 0 is a safe sentinel
    }

    for (int round = 0; round < 32; round++) {
        // per-thread argmax over remaining (strict '>' keeps earliest i = smallest m)
        unsigned bu = 0u; int bi = 0;
        #pragma unroll
        for (int i = 0; i < 32; i++)
            if (uq[i] > bu) { bu = uq[i]; bi = i; }
        unsigned long long key =
            ((unsigned long long)bu << 32) | (unsigned)(Md - 1 - (bi * 256 + t));
        #pragma unroll
        for (int o = 32; o > 0; o >>= 1) {
            unsigned long long other = __shfl_down(key, o);
            if (other > key) key = other;
        }
        const int p = round & 1;             // double-buffered cross-wave slots: 1 barrier/round
        if (lane == 0) wred[p][wav] = key;
        __syncthreads();
        unsigned long long best = wred[p][0];
        if (wred[p][1] > best) best = wred[p][1];
        if (wred[p][2] > best) best = wred[p][2];
        if (wred[p][3] > best) best = wred[p][3];
        const int m_win = Md - 1 - (int)(best & 0xFFFFFFFFull);
        if ((m_win & 255) == t) uq[m_win >> 8] = 0u;   // remove winner (own registers)
        if (t == 0) order[round] = m_win;
    }

    // gumbel argmax: f32 (Q + g), first-index tie-break (argmax semantics)
    unsigned bu = 0u; int bm = 0;
    #pragma unroll
    for (int i = 0; i < 32; i++) {
        unsigned us = f2u(qv[i] + G[i * 256 + t]);
        if (us > bu) { bu = us; bm = i * 256 + t; }
    }
    unsigned long long key = ((unsigned long long)bu << 32) | (unsigned)(Md - 1 - bm);
    #pragma unroll
    for (int o = 32; o > 0; o >>= 1) {
        unsigned long long other = __shfl_down(key, o);
        if (other > key) key = other;
    }
    if (lane == 0) wred[0][wav] = key;       // wred[0] last read before round-31 barrier: safe
    __syncthreads();                         // also makes order[] visible below
    unsigned long long best = wred[0][0];
    if (wred[0][1] > best) best = wred[0][1];
    if (wred[0][2] > best) best = wred[0][2];
    if (wred[0][3] > best) best = wred[0][3];
    const int am = Md - 1 - (int)(best & 0xFFFFFFFFull);

    int* st = (int*)(stash + (size_t)r * 64);
    if (t < 32)  st[t] = order[t];
    if (t == 32) st[32] = am;
}

// ---------------------------------------------------------------------------
// K5: Qg one-hot (overwrites the f32 logits). Reads argmax from stash.
// Exact forward value of y_hard - sg(y_soft) + y_soft: 0 off-argmax, 1 at argmax.
// ---------------------------------------------------------------------------
__global__ __launch_bounds__(256) void k5_onehot(
    float* __restrict__ qg, const float* __restrict__ sf)
{
    const int r = blockIdx.x;
    const int t = threadIdx.x;
    __shared__ int am_s;
    if (t == 0) am_s = ((const int*)(sf + (size_t)r * 64))[32];
    __syncthreads();
    const int am = am_s;
    const int q4 = am >> 2;
    float4* row = (float4*)(qg + (size_t)r * Md);
    #pragma unroll
    for (int i = 0; i < 8; i++) {
        int idx = i * 256 + t;
        float4 v = make_float4(0.f, 0.f, 0.f, 0.f);
        if (idx == q4) ((float*)&v)[am & 3] = 1.0f;
        row[idx] = v;
    }
}

// ---------------------------------------------------------------------------
// K4: gather outputs. Reads the stash row, then overwrites sampled_feature
// and grouped_feature (the h1 scratch region — h1 no longer needed).
// ---------------------------------------------------------------------------
__global__ __launch_bounds__(256) void k4_gather(
    const float* __restrict__ coord,
    const float* __restrict__ feat,
    float* __restrict__ out)
{
    const int r = blockIdx.x;
    const int b = r >> 10;
    const int t = threadIdx.x;
    __shared__ int idx[33];
    const int* st = (const int*)(out + OFF_SF + (size_t)r * 64);
    if (t < 33) idx[t] = st[t];
    __syncthreads();
    const int am = idx[32];

    if (t < 3)
        out[OFF_SP + (size_t)r * 3 + t] = coord[((size_t)b * Md + am) * 3 + t];
    if (t >= 32 && t < 128) {
        int e = t - 32;                       // 0..95
        int n = e / 3, c = e - n * 3;
        out[OFF_GP + (size_t)r * 96 + e] = coord[((size_t)b * Md + idx[n]) * 3 + c];
    }
    if (t >= 128 && t < 192) {
        int d = t - 128;
        float fv = feat[((size_t)b * Md + am) * Dd + d];
        out[OFF_SF + (size_t)r * 64 + d]   = fv;   // sampled_feature (overwrites stash)
        out[OFF_GF + (size_t)r * 2048 + d] = fv;   // grouped_feature[.,.,0,:]
    }
    for (int e = 64 + t; e < 2048; e += 256) {
        int n = e >> 6, d = e & 63;
        out[OFF_GF + (size_t)r * 2048 + e] = feat[((size_t)b * Md + idx[n]) * Dd + d];
    }
}

// ---------------------------------------------------------------------------
extern "C" void kernel_launch(void* const* d_in, const int* in_sizes, int n_in,
                              void* d_out, int out_size, void* d_ws, size_t ws_size,
                              hipStream_t stream)
{
    (void)in_sizes; (void)n_in; (void)out_size; (void)d_ws; (void)ws_size;
    const float* coord = (const float*)d_in[0];
    const float* feat  = (const float*)d_in[1];
    const float* gum   = (const float*)d_in[2];
    const float* w0    = (const float*)d_in[3];
    const float* g0    = (const float*)d_in[4];
    const float* be0   = (const float*)d_in[5];
    const float* mu0   = (const float*)d_in[6];
    const float* va0   = (const float*)d_in[7];
    const float* w1    = (const float*)d_in[8];
    const float* g1    = (const float*)d_in[9];
    const float* be1   = (const float*)d_in[10];
    const float* mu1   = (const float*)d_in[11];
    const float* va1   = (const float*)d_in[12];
    const float* w2    = (const float*)d_in[13];

    float*  out    = (float*)d_out;
    float*  h1ws   = out + OFF_GF;              // f32 h1 scratch (16MB of the 32MB GF region)
    float*  logits = out + OFF_QG;              // f32 logits / later Qg
    float*  stash  = out + OFF_SF;              // idx stash / later sampled_feature

    k1_mlp   <<<dim3(128),     dim3(256), 0, stream>>>(coord, w0, g0, be0, mu0, va0,
                                                       w1, g1, be1, mu1, va1, h1ws);
    k2_gemm  <<<dim3(2048, 4), dim3(256), 0, stream>>>(h1ws, w2, logits);
    k3_select<<<dim3(4096),    dim3(256), 0, stream>>>(logits, gum, stash);
    k5_onehot<<<dim3(4096),    dim3(256), 0, stream>>>(logits, stash);
    k4_gather<<<dim3(4096),    dim3(256), 0, stream>>>(coord, feat, out);
}

// Round 6
// 283.744 us; speedup vs baseline: 1.4943x; 1.4943x over previous
//
#include <hip/hip_runtime.h>
#include <math.h>

// Problem constants
#define Bd   4
#define Md   8192
#define Dd   64
#define Sd   1024
#define H0d  32
#define H1d  128

// d_out layout (float offsets), return order:
// sampled_points (B,S,3) | grouped_points (B,S,32,3) | sampled_feature (B,S,64)
// | grouped_feature (B,S,32,64) | Qg (B,S,M)
#define OFF_SP 0
#define OFF_GP 12288
#define OFF_SF 405504
#define OFF_GF 667648          // holds f32 h1 scratch (32768*128 floats = 16MB) until k3 overwrites
#define OFF_QG 9056256         // holds f32 logits [B][S][M] until one-hot overwrite

#define CAP 512                // candidate cap (expected n ~150)

// order-preserving float -> sortable u32
__device__ __forceinline__ unsigned f2u(float f) {
    unsigned v = __float_as_uint(f);
    return (v & 0x80000000u) ? ~v : (v | 0x80000000u);
}

// ---------------------------------------------------------------------------
// K1: per-point MLP (f64 internal math, f32 output).  [unchanged, verified]
// ---------------------------------------------------------------------------
__global__ __launch_bounds__(256) void k1_mlp(
    const float* __restrict__ coord,
    const float* __restrict__ w0,
    const float* __restrict__ g0, const float* __restrict__ be0,
    const float* __restrict__ mu0, const float* __restrict__ va0,
    const float* __restrict__ w1,
    const float* __restrict__ g1, const float* __restrict__ be1,
    const float* __restrict__ mu1, const float* __restrict__ va1,
    float* __restrict__ h1out)
{
    __shared__ double W1[H0d * H1d];
    __shared__ double W0[5 * H0d];
    __shared__ double MU0[H0d], RS0[H0d], BE0[H0d];
    __shared__ double MU1[H1d], RS1[H1d], BE1[H1d];
    const int t = threadIdx.x;
    for (int i = t; i < H0d * H1d; i += 256) W1[i] = (double)w1[i];
    if (t < 5 * H0d) W0[t] = (double)w0[t];
    if (t < H0d) {
        MU0[t] = (double)mu0[t];
        RS0[t] = (double)g0[t] / sqrt((double)va0[t] + 1e-5);
        BE0[t] = (double)be0[t];
    }
    if (t >= 128) {
        int j = t - 128;
        MU1[j] = (double)mu1[j];
        RS1[j] = (double)g1[j] / sqrt((double)va1[j] + 1e-5);
        BE1[j] = (double)be1[j];
    }
    __syncthreads();

    const int p = blockIdx.x * 256 + t;      // 0..32767  (= b*M + m)
    const double x = (double)coord[p * 3 + 0];
    const double y = (double)coord[p * 3 + 1];
    const double z = (double)coord[p * 3 + 2];
    const double r  = sqrt(x * x + y * y + z * z);
    const double th = acos(z / r);
    const double fi = atan2(y, x);

    double h0[H0d];
    #pragma unroll
    for (int i = 0; i < H0d; i++) {
        double a = x * W0[i] + y * W0[H0d + i] + z * W0[2 * H0d + i]
                 + th * W0[3 * H0d + i] + fi * W0[4 * H0d + i];
        a = (a - MU0[i]) * RS0[i] + BE0[i];
        h0[i] = a > 0.0 ? a : 0.0;
    }
    float* o = h1out + (size_t)p * H1d;
    for (int j = 0; j < H1d; j += 2) {
        double a0 = 0.0, a1 = 0.0;
        #pragma unroll
        for (int i = 0; i < H0d; i++) {
            double h = h0[i];
            a0 += h * W1[i * H1d + j];
            a1 += h * W1[i * H1d + j + 1];
        }
        a0 = (a0 - MU1[j]) * RS1[j] + BE1[j];             a0 = a0 > 0.0 ? a0 : 0.0;
        a1 = (a1 - MU1[j + 1]) * RS1[j + 1] + BE1[j + 1]; a1 = a1 > 0.0 ? a1 : 0.0;
        o[j] = (float)a0; o[j + 1] = (float)a1;
    }
}

// ---------------------------------------------------------------------------
// K2: f32 GEMM.  logits[b][s][m] = sum_k h1[b][m][k] * w2[k][s]  [unchanged]
// ---------------------------------------------------------------------------
__global__ __launch_bounds__(256) void k2_gemm(
    const float* __restrict__ h1,
    const float* __restrict__ w2,
    float* __restrict__ logits)
{
    __shared__ float As[128 * 64];           // 32 KB, [k][m] XOR-swizzled
    const int bx = blockIdx.x, b = blockIdx.y;
    const int stile = bx & 15, mtile = bx >> 4;
    const int m0 = mtile * 64, s0 = stile * 64;
    const int t = threadIdx.x;

    const float* Ab = h1 + ((size_t)b * Md + m0) * H1d;
    for (int e = t; e < 2048; e += 256) {
        int row = e >> 5;                    // 0..63
        int k4  = e & 31;                    // 0..31
        float4 v = *(const float4*)&Ab[(size_t)row * H1d + k4 * 4];
        #pragma unroll
        for (int j = 0; j < 4; j++) {
            int k = k4 * 4 + j;
            As[k * 64 + ((((row >> 2) ^ (k & 15)) << 2) | (row & 3))] = ((const float*)&v)[j];
        }
    }
    __syncthreads();

    const int mq = t & 15, sq = t >> 4;
    float acc[4][4] = {};
    #pragma unroll 8
    for (int k = 0; k < 128; k++) {
        float4 a  = *(const float4*)&As[k * 64 + ((mq ^ (k & 15)) << 2)];
        float4 bb = *(const float4*)&w2[(size_t)k * Sd + s0 + sq * 4];
        acc[0][0] += bb.x * a.x; acc[0][1] += bb.x * a.y; acc[0][2] += bb.x * a.z; acc[0][3] += bb.x * a.w;
        acc[1][0] += bb.y * a.x; acc[1][1] += bb.y * a.y; acc[1][2] += bb.y * a.z; acc[1][3] += bb.y * a.w;
        acc[2][0] += bb.z * a.x; acc[2][1] += bb.z * a.y; acc[2][2] += bb.z * a.z; acc[2][3] += bb.z * a.w;
        acc[3][0] += bb.w * a.x; acc[3][1] += bb.w * a.y; acc[3][2] += bb.w * a.z; acc[3][3] += bb.w * a.w;
    }
    float* C = logits + ((size_t)b * Sd + s0) * Md + m0;
    #pragma unroll
    for (int si = 0; si < 4; si++) {
        float4 v = make_float4(acc[si][0], acc[si][1], acc[si][2], acc[si][3]);
        *(float4*)&C[(size_t)(sq * 4 + si) * Md + mq * 4] = v;
    }
}

// ---------------------------------------------------------------------------
// K3 (fused): selection + one-hot + gather, one block per (b,s) row.
//
// Selection: threshold filter + rank-count.
//   T = max over waves of (32nd-largest of the wave's 64 per-lane maxima).
//   Theorem: T > tau(row 32nd-largest) would imply >=32 distinct elements
//   > tau — contradiction — so T <= tau and {x >= T} ⊇ top-32.
//   Self-check: T > tau  <=>  count(x >= T) < 32, so the guard
//   (n < 32 || n > CAP) -> verified iterative fallback makes correctness
//   independent of the bitonic network.
//   Rank-count on u64 keys (uq<<32 | 8191-m) reproduces top_k order exactly
//   (desc value, lower index on ties); deterministic regardless of the
//   atomic collection order.
// ---------------------------------------------------------------------------
__global__ __launch_bounds__(256) void k3_fused(
    float* __restrict__ logits,              // row r read, then overwritten with Qg
    const float* __restrict__ gumbel,
    const float* __restrict__ coord,
    const float* __restrict__ feat,
    float* __restrict__ out)
{
    const int r = blockIdx.x;                // 0..4095
    const int b = r >> 10;
    const int t = threadIdx.x;
    const int lane = t & 63, wav = t >> 6;
    const float* L = logits + (size_t)r * Md;
    const float* G = gumbel + (size_t)r * Md;

    __shared__ unsigned long long wred[2][4];
    __shared__ unsigned long long ck[CAP];
    __shared__ unsigned swT[4];
    __shared__ int cnt;
    __shared__ int order[32];

    // ---- load + sigmoid (exact round-5 arithmetic: ranking domain) ----
    unsigned uq[32];
    #pragma unroll
    for (int i = 0; i < 32; i++) {
        float x = L[i * 256 + t];
        float q = 1.0f / (1.0f + expf(-x));
        uq[i] = f2u(q);                      // q>0 -> top bit set; 0 is a safe sentinel
    }

    // ---- gumbel argmax FIRST (uq still pristine; q recovered by bit-twiddle) ----
    {
        unsigned bu = 0u; int bm = 0;
        #pragma unroll
        for (int i = 0; i < 32; i++) {
            float q = __uint_as_float(uq[i] ^ 0x80000000u);   // inverse of f2u for q>=0
            unsigned us = f2u(q + G[i * 256 + t]);
            if (us > bu) { bu = us; bm = i * 256 + t; }
        }
        unsigned long long key = ((unsigned long long)bu << 32) | (unsigned)(Md - 1 - bm);
        #pragma unroll
        for (int o = 32; o > 0; o >>= 1) {
            unsigned long long other = __shfl_down(key, o);
            if (other > key) key = other;
        }
        if (lane == 0) wred[0][wav] = key;
    }
    if (t == 0) cnt = 0;
    __syncthreads();                         // B1: wred[0], cnt
    unsigned long long gbest = wred[0][0];
    if (wred[0][1] > gbest) gbest = wred[0][1];
    if (wred[0][2] > gbest) gbest = wred[0][2];
    if (wred[0][3] > gbest) gbest = wred[0][3];
    const int am = Md - 1 - (int)(gbest & 0xFFFFFFFFull);

    // ---- per-thread max, wave bitonic sort of 64 lane-maxima ----
    unsigned pm = 0u;
    #pragma unroll
    for (int i = 0; i < 32; i++) pm = max(pm, uq[i]);
    unsigned v = pm;
    #pragma unroll
    for (int k = 2; k <= 64; k <<= 1) {
        #pragma unroll
        for (int j = k >> 1; j > 0; j >>= 1) {
            unsigned o = __shfl_xor(v, j);
            bool up = ((lane & k) == 0);
            bool lower = ((lane & j) == 0);
            unsigned mn = min(v, o), mx = max(v, o);
            v = (lower == up) ? mn : mx;     // ascending by lane after final pass
        }
    }
    unsigned tw = __shfl(v, 32);             // asc pos 32 = desc rank 31 (32nd largest)
    if (lane == 0) swT[wav] = tw;
    __syncthreads();                         // B2: swT
    const unsigned T = max(max(swT[0], swT[1]), max(swT[2], swT[3]));

    // ---- collect candidates >= T ----
    #pragma unroll
    for (int i = 0; i < 32; i++) {
        if (uq[i] >= T) {
            int pos = atomicAdd(&cnt, 1);
            if (pos < CAP)
                ck[pos] = ((unsigned long long)uq[i] << 32)
                        | (unsigned)(Md - 1 - (i * 256 + t));
        }
    }
    __syncthreads();                         // B3: ck, cnt
    const int n = cnt;

    if (n >= 32 && n <= CAP) {
        // ---- fast path: O(n^2) rank-count, n ~ 150 ----
        for (int j2 = t; j2 < n; j2 += 256) {
            unsigned long long mine = ck[j2];
            int rk = 0;
            for (int i2 = 0; i2 < n; i2++) rk += (ck[i2] > mine) ? 1 : 0;
            if (rk < 32) order[rk] = Md - 1 - (int)(mine & 0xFFFFFFFFull);
        }
    } else {
        // ---- fallback: verified round-5 iterative extraction ----
        for (int round = 0; round < 32; round++) {
            unsigned bu = 0u; int bi = 0;
            #pragma unroll
            for (int i = 0; i < 32; i++)
                if (uq[i] > bu) { bu = uq[i]; bi = i; }
            unsigned long long key =
                ((unsigned long long)bu << 32) | (unsigned)(Md - 1 - (bi * 256 + t));
            #pragma unroll
            for (int o = 32; o > 0; o >>= 1) {
                unsigned long long other = __shfl_down(key, o);
                if (other > key) key = other;
            }
            const int p = round & 1;
            if (lane == 0) wred[p][wav] = key;
            __syncthreads();
            unsigned long long best = wred[p][0];
            if (wred[p][1] > best) best = wred[p][1];
            if (wred[p][2] > best) best = wred[p][2];
            if (wred[p][3] > best) best = wred[p][3];
            const int m_win = Md - 1 - (int)(best & 0xFFFFFFFFull);
            if ((m_win & 255) == t) uq[m_win >> 8] = 0u;
            if (t == 0) order[round] = m_win;
        }
    }
    __syncthreads();                         // B4: order[] visible

    // ---- outputs ----
    // Qg one-hot (overwrites this block's own logits row — safe, row-exclusive)
    {
        const int q4 = am >> 2;
        float4* row = (float4*)(logits + (size_t)r * Md);
        #pragma unroll
        for (int i = 0; i < 8; i++) {
            int idx = i * 256 + t;
            float4 vv = make_float4(0.f, 0.f, 0.f, 0.f);
            if (idx == q4) ((float*)&vv)[am & 3] = 1.0f;
            row[idx] = vv;
        }
    }
    if (t < 3)
        out[OFF_SP + (size_t)r * 3 + t] = coord[((size_t)b * Md + am) * 3 + t];
    if (t >= 32 && t < 128) {
        int e = t - 32;                      // 0..95
        int nn = e / 3, c = e - nn * 3;
        out[OFF_GP + (size_t)r * 96 + e] = coord[((size_t)b * Md + order[nn]) * 3 + c];
    }
    if (t >= 128 && t < 192) {
        int d = t - 128;
        float fv = feat[((size_t)b * Md + am) * Dd + d];
        out[OFF_SF + (size_t)r * 64 + d]   = fv;   // sampled_feature
        out[OFF_GF + (size_t)r * 2048 + d] = fv;   // grouped_feature[.,.,0,:]
    }
    for (int e = 64 + t; e < 2048; e += 256) {
        int nn = e >> 6, d = e & 63;
        out[OFF_GF + (size_t)r * 2048 + e] = feat[((size_t)b * Md + order[nn]) * Dd + d];
    }
}

// ---------------------------------------------------------------------------
extern "C" void kernel_launch(void* const* d_in, const int* in_sizes, int n_in,
                              void* d_out, int out_size, void* d_ws, size_t ws_size,
                              hipStream_t stream)
{
    (void)in_sizes; (void)n_in; (void)out_size; (void)d_ws; (void)ws_size;
    const float* coord = (const float*)d_in[0];
    const float* feat  = (const float*)d_in[1];
    const float* gum   = (const float*)d_in[2];
    const float* w0    = (const float*)d_in[3];
    const float* g0    = (const float*)d_in[4];
    const float* be0   = (const float*)d_in[5];
    const float* mu0   = (const float*)d_in[6];
    const float* va0   = (const float*)d_in[7];
    const float* w1    = (const float*)d_in[8];
    const float* g1    = (const float*)d_in[9];
    const float* be1   = (const float*)d_in[10];
    const float* mu1   = (const float*)d_in[11];
    const float* va1   = (const float*)d_in[12];
    const float* w2    = (const float*)d_in[13];

    float*  out    = (float*)d_out;
    float*  h1ws   = out + OFF_GF;              // f32 h1 scratch (overwritten by k3 gather)
    float*  logits = out + OFF_QG;              // f32 logits -> Qg one-hot

    k1_mlp   <<<dim3(128),     dim3(256), 0, stream>>>(coord, w0, g0, be0, mu0, va0,
                                                       w1, g1, be1, mu1, va1, h1ws);
    k2_gemm  <<<dim3(2048, 4), dim3(256), 0, stream>>>(h1ws, w2, logits);
    k3_fused <<<dim3(4096),    dim3(256), 0, stream>>>(logits, gum, coord, feat, out);
}

// Round 7
// 230.942 us; speedup vs baseline: 1.8360x; 1.2286x over previous
//
#include <hip/hip_runtime.h>
#include <math.h>

// Problem constants
#define Bd   4
#define Md   8192
#define Dd   64
#define Sd   1024
#define H0d  32
#define H1d  128

// d_out layout (float offsets), return order:
// sampled_points (B,S,3) | grouped_points (B,S,32,3) | sampled_feature (B,S,64)
// | grouped_feature (B,S,32,64) | Qg (B,S,M)
#define OFF_SP 0
#define OFF_GP 12288
#define OFF_SF 405504
#define OFF_GF 667648          // holds f32 h1T scratch [b][k][m] (16.8MB of 33.5MB) until k3 overwrites
#define OFF_QG 9056256         // holds f32 logits [B][S][M] until one-hot overwrite

#define CAP 512                // candidate cap (expected n ~150)

// order-preserving float -> sortable u32
__device__ __forceinline__ unsigned f2u(float f) {
    unsigned v = __float_as_uint(f);
    return (v & 0x80000000u) ? ~v : (v | 0x80000000u);
}

// ---------------------------------------------------------------------------
// K1: per-point MLP (f64 internal math, f32 output) — math identical to the
// verified version; output now TRANSPOSED: h1T[b][k][m] (m contiguous), so
// k2's LDS staging is stride-1 (no transpose, no bank conflicts).
// ---------------------------------------------------------------------------
__global__ __launch_bounds__(256) void k1_mlp(
    const float* __restrict__ coord,
    const float* __restrict__ w0,
    const float* __restrict__ g0, const float* __restrict__ be0,
    const float* __restrict__ mu0, const float* __restrict__ va0,
    const float* __restrict__ w1,
    const float* __restrict__ g1, const float* __restrict__ be1,
    const float* __restrict__ mu1, const float* __restrict__ va1,
    float* __restrict__ h1T)
{
    __shared__ double W1[H0d * H1d];
    __shared__ double W0[5 * H0d];
    __shared__ double MU0[H0d], RS0[H0d], BE0[H0d];
    __shared__ double MU1[H1d], RS1[H1d], BE1[H1d];
    const int t = threadIdx.x;
    for (int i = t; i < H0d * H1d; i += 256) W1[i] = (double)w1[i];
    if (t < 5 * H0d) W0[t] = (double)w0[t];
    if (t < H0d) {
        MU0[t] = (double)mu0[t];
        RS0[t] = (double)g0[t] / sqrt((double)va0[t] + 1e-5);
        BE0[t] = (double)be0[t];
    }
    if (t >= 128) {
        int j = t - 128;
        MU1[j] = (double)mu1[j];
        RS1[j] = (double)g1[j] / sqrt((double)va1[j] + 1e-5);
        BE1[j] = (double)be1[j];
    }
    __syncthreads();

    const int p = blockIdx.x * 256 + t;      // 0..32767  (= b*M + m)
    const double x = (double)coord[p * 3 + 0];
    const double y = (double)coord[p * 3 + 1];
    const double z = (double)coord[p * 3 + 2];
    const double r  = sqrt(x * x + y * y + z * z);
    const double th = acos(z / r);
    const double fi = atan2(y, x);

    double h0[H0d];
    #pragma unroll
    for (int i = 0; i < H0d; i++) {
        double a = x * W0[i] + y * W0[H0d + i] + z * W0[2 * H0d + i]
                 + th * W0[3 * H0d + i] + fi * W0[4 * H0d + i];
        a = (a - MU0[i]) * RS0[i] + BE0[i];
        h0[i] = a > 0.0 ? a : 0.0;
    }
    float* o = h1T + (size_t)(p >> 13) * (H1d * Md) + (p & (Md - 1));
    for (int j = 0; j < H1d; j += 2) {
        double a0 = 0.0, a1 = 0.0;
        #pragma unroll
        for (int i = 0; i < H0d; i++) {
            double h = h0[i];
            a0 += h * W1[i * H1d + j];
            a1 += h * W1[i * H1d + j + 1];
        }
        a0 = (a0 - MU1[j]) * RS1[j] + BE1[j];             a0 = a0 > 0.0 ? a0 : 0.0;
        a1 = (a1 - MU1[j + 1]) * RS1[j + 1] + BE1[j + 1]; a1 = a1 > 0.0 ? a1 : 0.0;
        o[(size_t)j * Md]       = (float)a0;
        o[(size_t)(j + 1) * Md] = (float)a1;
    }
}

// ---------------------------------------------------------------------------
// K2: f32 GEMM, 128x128 tile, 8x8 per thread, BK=64 x 2 steps, A+B in LDS.
// logits[b][s][m] = sum_k h1T[b][k][m] * w2[k][s], k ascending per output
// (bitwise-identical accumulation order to the verified kernel).
// Fragments are strided (m = tm*4 and 64+tm*4): LDS reads are 2-way (free),
// staging is stride-1 float4 (conflict-free). 64 KB LDS -> 2 blocks/CU.
// ---------------------------------------------------------------------------
__global__ __launch_bounds__(256) void k2_gemm(
    const float* __restrict__ h1T,
    const float* __restrict__ w2,
    float* __restrict__ logits)
{
    __shared__ float As[64][128];            // 32 KB
    __shared__ float Bs[64][128];            // 32 KB
    const int bx = blockIdx.x, b = blockIdx.y;
    const int mtile = bx & 63, stile = bx >> 6;   // mtile fast: same-A blocks 64 apart -> same XCD
    const int m0 = mtile * 128, s0 = stile * 128;
    const int t = threadIdx.x;
    const int tm = t & 15, tn = t >> 4;

    float acc[8][8] = {};

    for (int kt = 0; kt < 2; kt++) {
        const float* Ag = h1T + ((size_t)b * H1d + kt * 64) * Md + m0;
        const float* Bg = w2 + (size_t)(kt * 64) * Sd + s0;
        #pragma unroll
        for (int i = 0; i < 8; i++) {
            int idx = t + i * 256;
            int kk = idx >> 5, c = idx & 31;
            *(float4*)&As[kk][c * 4] = *(const float4*)&Ag[(size_t)kk * Md + c * 4];
            *(float4*)&Bs[kk][c * 4] = *(const float4*)&Bg[(size_t)kk * Sd + c * 4];
        }
        __syncthreads();

        #pragma unroll 8
        for (int k = 0; k < 64; k++) {
            float a_[8], b_[8];
            *(float4*)&a_[0] = *(const float4*)&As[k][tm * 4];
            *(float4*)&a_[4] = *(const float4*)&As[k][64 + tm * 4];
            *(float4*)&b_[0] = *(const float4*)&Bs[k][tn * 4];
            *(float4*)&b_[4] = *(const float4*)&Bs[k][64 + tn * 4];
            #pragma unroll
            for (int si = 0; si < 8; si++)
                #pragma unroll
                for (int mi = 0; mi < 8; mi++)
                    acc[si][mi] += b_[si] * a_[mi];
        }
        __syncthreads();
    }

    #pragma unroll
    for (int si = 0; si < 8; si++) {
        int s = s0 + (si >> 2) * 64 + tn * 4 + (si & 3);
        float* row = logits + ((size_t)b * Sd + s) * Md + m0;
        *(float4*)&row[tm * 4]      = make_float4(acc[si][0], acc[si][1], acc[si][2], acc[si][3]);
        *(float4*)&row[64 + tm * 4] = make_float4(acc[si][4], acc[si][5], acc[si][6], acc[si][7]);
    }
}

// ---------------------------------------------------------------------------
// K3 (fused): selection + one-hot + gather, one block per (b,s) row.
// Same verified threshold-filter + rank-count machinery; loads vectorized to
// float4. Lane->m mapping: m(i,t) = (i>>2)*1024 + t*4 + (i&3) (re-partition
// only; per-element arithmetic identical, threshold theorem unaffected).
// ---------------------------------------------------------------------------
__global__ __launch_bounds__(256) void k3_fused(
    float* __restrict__ logits,              // row r read, then overwritten with Qg
    const float* __restrict__ gumbel,
    const float* __restrict__ coord,
    const float* __restrict__ feat,
    float* __restrict__ out)
{
    const int r = blockIdx.x;                // 0..4095
    const int b = r >> 10;
    const int t = threadIdx.x;
    const int lane = t & 63, wav = t >> 6;
    const float4* L4 = (const float4*)(logits + (size_t)r * Md);
    const float4* G4 = (const float4*)(gumbel + (size_t)r * Md);

    __shared__ unsigned long long wred[2][4];
    __shared__ unsigned long long ck[CAP];
    __shared__ unsigned swT[4];
    __shared__ int cnt;
    __shared__ int order[32];

    // ---- load + sigmoid + inline gumbel scan (float4, 16B/lane) ----
    unsigned uq[32];
    unsigned gbu = 0u; int gbm = 0;
    #pragma unroll
    for (int j = 0; j < 8; j++) {
        float4 v = L4[j * 256 + t];
        float4 g = G4[j * 256 + t];
        #pragma unroll
        for (int c = 0; c < 4; c++) {
            float x = ((const float*)&v)[c];
            float q = 1.0f / (1.0f + expf(-x));
            uq[j * 4 + c] = f2u(q);          // q>0 -> top bit set; 0 is a safe sentinel
            unsigned us = f2u(q + ((const float*)&g)[c]);
            if (us > gbu) { gbu = us; gbm = j * 1024 + t * 4 + c; }
        }
    }

    // ---- gumbel argmax reduce (first max -> smallest m via inverted-index key) ----
    {
        unsigned long long key = ((unsigned long long)gbu << 32) | (unsigned)(Md - 1 - gbm);
        #pragma unroll
        for (int o = 32; o > 0; o >>= 1) {
            unsigned long long other = __shfl_down(key, o);
            if (other > key) key = other;
        }
        if (lane == 0) wred[0][wav] = key;
    }
    if (t == 0) cnt = 0;
    __syncthreads();                         // B1: wred[0], cnt
    unsigned long long gbest = wred[0][0];
    if (wred[0][1] > gbest) gbest = wred[0][1];
    if (wred[0][2] > gbest) gbest = wred[0][2];
    if (wred[0][3] > gbest) gbest = wred[0][3];
    const int am = Md - 1 - (int)(gbest & 0xFFFFFFFFull);

    // ---- per-thread max, wave bitonic sort of 64 lane-maxima -> threshold T ----
    unsigned pm = 0u;
    #pragma unroll
    for (int i = 0; i < 32; i++) pm = max(pm, uq[i]);
    unsigned v = pm;
    #pragma unroll
    for (int k = 2; k <= 64; k <<= 1) {
        #pragma unroll
        for (int j = k >> 1; j > 0; j >>= 1) {
            unsigned o = __shfl_xor(v, j);
            bool up = ((lane & k) == 0);
            bool lower = ((lane & j) == 0);
            unsigned mn = min(v, o), mx = max(v, o);
            v = (lower == up) ? mn : mx;     // ascending by lane after final pass
        }
    }
    unsigned tw = __shfl(v, 32);             // asc pos 32 = 32nd largest of the wave
    if (lane == 0) swT[wav] = tw;
    __syncthreads();                         // B2: swT
    const unsigned T = max(max(swT[0], swT[1]), max(swT[2], swT[3]));

    // ---- collect candidates >= T ----
    #pragma unroll
    for (int i = 0; i < 32; i++) {
        if (uq[i] >= T) {
            int pos = atomicAdd(&cnt, 1);
            if (pos < CAP) {
                int m = (i >> 2) * 1024 + t * 4 + (i & 3);
                ck[pos] = ((unsigned long long)uq[i] << 32) | (unsigned)(Md - 1 - m);
            }
        }
    }
    __syncthreads();                         // B3: ck, cnt
    const int n = cnt;

    if (n >= 32 && n <= CAP) {
        // ---- fast path: O(n^2) rank-count ----
        for (int j2 = t; j2 < n; j2 += 256) {
            unsigned long long mine = ck[j2];
            int rk = 0;
            for (int i2 = 0; i2 < n; i2++) rk += (ck[i2] > mine) ? 1 : 0;
            if (rk < 32) order[rk] = Md - 1 - (int)(mine & 0xFFFFFFFFull);
        }
    } else {
        // ---- fallback: verified iterative extraction (new mapping) ----
        for (int round = 0; round < 32; round++) {
            unsigned bu = 0u; int bi = 0;
            #pragma unroll
            for (int i = 0; i < 32; i++)
                if (uq[i] > bu) { bu = uq[i]; bi = i; }
            int bm = (bi >> 2) * 1024 + t * 4 + (bi & 3);
            unsigned long long key =
                ((unsigned long long)bu << 32) | (unsigned)(Md - 1 - bm);
            #pragma unroll
            for (int o = 32; o > 0; o >>= 1) {
                unsigned long long other = __shfl_down(key, o);
                if (other > key) key = other;
            }
            const int p = round & 1;
            if (lane == 0) wred[p][wav] = key;
            __syncthreads();
            unsigned long long best = wred[p][0];
            if (wred[p][1] > best) best = wred[p][1];
            if (wred[p][2] > best) best = wred[p][2];
            if (wred[p][3] > best) best = wred[p][3];
            const int m_win = Md - 1 - (int)(best & 0xFFFFFFFFull);
            if (((m_win >> 2) & 255) == t)
                uq[(m_win >> 10) * 4 + (m_win & 3)] = 0u;
            if (t == 0) order[round] = m_win;
        }
    }
    __syncthreads();                         // B4: order[] visible

    // ---- outputs ----
    // Qg one-hot (overwrites this block's own logits row)
    {
        const int q4 = am >> 2;
        float4* row = (float4*)(logits + (size_t)r * Md);
        #pragma unroll
        for (int i = 0; i < 8; i++) {
            int idx = i * 256 + t;
            float4 vv = make_float4(0.f, 0.f, 0.f, 0.f);
            if (idx == q4) ((float*)&vv)[am & 3] = 1.0f;
            row[idx] = vv;
        }
    }
    if (t < 3)
        out[OFF_SP + (size_t)r * 3 + t] = coord[((size_t)b * Md + am) * 3 + t];
    if (t >= 32 && t < 128) {
        int e = t - 32;                      // 0..95
        int nn = e / 3, c = e - nn * 3;
        out[OFF_GP + (size_t)r * 96 + e] = coord[((size_t)b * Md + order[nn]) * 3 + c];
    }
    const float4* F4  = (const float4*)feat;          // feat row = 16 float4
    float4* SF4 = (float4*)(out + OFF_SF);
    float4* GF4 = (float4*)(out + OFF_GF);
    if (t < 16) {
        float4 fv = F4[((size_t)b * Md + am) * 16 + t];
        SF4[(size_t)r * 16 + t]  = fv;       // sampled_feature
        GF4[(size_t)r * 512 + t] = fv;       // grouped_feature[.,.,0,:]
    }
    for (int e4 = 16 + t; e4 < 512; e4 += 256) {
        int nn = e4 >> 4, d4 = e4 & 15;
        GF4[(size_t)r * 512 + e4] = F4[((size_t)b * Md + order[nn]) * 16 + d4];
    }
}

// ---------------------------------------------------------------------------
extern "C" void kernel_launch(void* const* d_in, const int* in_sizes, int n_in,
                              void* d_out, int out_size, void* d_ws, size_t ws_size,
                              hipStream_t stream)
{
    (void)in_sizes; (void)n_in; (void)out_size; (void)d_ws; (void)ws_size;
    const float* coord = (const float*)d_in[0];
    const float* feat  = (const float*)d_in[1];
    const float* gum   = (const float*)d_in[2];
    const float* w0    = (const float*)d_in[3];
    const float* g0    = (const float*)d_in[4];
    const float* be0   = (const float*)d_in[5];
    const float* mu0   = (const float*)d_in[6];
    const float* va0   = (const float*)d_in[7];
    const float* w1    = (const float*)d_in[8];
    const float* g1    = (const float*)d_in[9];
    const float* be1   = (const float*)d_in[10];
    const float* mu1   = (const float*)d_in[11];
    const float* va1   = (const float*)d_in[12];
    const float* w2    = (const float*)d_in[13];

    float*  out    = (float*)d_out;
    float*  h1T    = out + OFF_GF;              // f32 h1T scratch (overwritten by k3 gather)
    float*  logits = out + OFF_QG;              // f32 logits -> Qg one-hot

    k1_mlp   <<<dim3(128),     dim3(256), 0, stream>>>(coord, w0, g0, be0, mu0, va0,
                                                       w1, g1, be1, mu1, va1, h1T);
    k2_gemm  <<<dim3(512, 4),  dim3(256), 0, stream>>>(h1T, w2, logits);
    k3_fused <<<dim3(4096),    dim3(256), 0, stream>>>(logits, gum, coord, feat, out);
}

// Round 9
// 226.566 us; speedup vs baseline: 1.8714x; 1.0193x over previous
//
#include <hip/hip_runtime.h>
#include <math.h>

// Problem constants
#define Bd   4
#define Md   8192
#define Dd   64
#define Sd   1024
#define H0d  32
#define H1d  128

// d_out layout (float offsets), return order:
// sampled_points (B,S,3) | grouped_points (B,S,32,3) | sampled_feature (B,S,64)
// | grouped_feature (B,S,32,64) | Qg (B,S,M)
#define OFF_SP 0
#define OFF_GP 12288
#define OFF_SF 405504
#define OFF_GF 667648          // holds f32 h1T scratch [b][k][m] (16.8MB of 33.5MB) until k3 overwrites
#define OFF_QG 9056256         // holds f32 logits [B][S][M] until one-hot overwrite

#define CAP 512                // candidate cap (expected n ~150)

// order-preserving float -> sortable u32
__device__ __forceinline__ unsigned f2u(float f) {
    unsigned v = __float_as_uint(f);
    return (v & 0x80000000u) ? ~v : (v | 0x80000000u);
}

// ---------------------------------------------------------------------------
// K1: per-point MLP (f64 internal math, f32 output), transposed output
// h1T[b][k][m] (m contiguous).  [unchanged, verified]
// ---------------------------------------------------------------------------
__global__ __launch_bounds__(256) void k1_mlp(
    const float* __restrict__ coord,
    const float* __restrict__ w0,
    const float* __restrict__ g0, const float* __restrict__ be0,
    const float* __restrict__ mu0, const float* __restrict__ va0,
    const float* __restrict__ w1,
    const float* __restrict__ g1, const float* __restrict__ be1,
    const float* __restrict__ mu1, const float* __restrict__ va1,
    float* __restrict__ h1T)
{
    __shared__ double W1[H0d * H1d];
    __shared__ double W0[5 * H0d];
    __shared__ double MU0[H0d], RS0[H0d], BE0[H0d];
    __shared__ double MU1[H1d], RS1[H1d], BE1[H1d];
    const int t = threadIdx.x;
    for (int i = t; i < H0d * H1d; i += 256) W1[i] = (double)w1[i];
    if (t < 5 * H0d) W0[t] = (double)w0[t];
    if (t < H0d) {
        MU0[t] = (double)mu0[t];
        RS0[t] = (double)g0[t] / sqrt((double)va0[t] + 1e-5);
        BE0[t] = (double)be0[t];
    }
    if (t >= 128) {
        int j = t - 128;
        MU1[j] = (double)mu1[j];
        RS1[j] = (double)g1[j] / sqrt((double)va1[j] + 1e-5);
        BE1[j] = (double)be1[j];
    }
    __syncthreads();

    const int p = blockIdx.x * 256 + t;      // 0..32767  (= b*M + m)
    const double x = (double)coord[p * 3 + 0];
    const double y = (double)coord[p * 3 + 1];
    const double z = (double)coord[p * 3 + 2];
    const double r  = sqrt(x * x + y * y + z * z);
    const double th = acos(z / r);
    const double fi = atan2(y, x);

    double h0[H0d];
    #pragma unroll
    for (int i = 0; i < H0d; i++) {
        double a = x * W0[i] + y * W0[H0d + i] + z * W0[2 * H0d + i]
                 + th * W0[3 * H0d + i] + fi * W0[4 * H0d + i];
        a = (a - MU0[i]) * RS0[i] + BE0[i];
        h0[i] = a > 0.0 ? a : 0.0;
    }
    float* o = h1T + (size_t)(p >> 13) * (H1d * Md) + (p & (Md - 1));
    for (int j = 0; j < H1d; j += 2) {
        double a0 = 0.0, a1 = 0.0;
        #pragma unroll
        for (int i = 0; i < H0d; i++) {
            double h = h0[i];
            a0 += h * W1[i * H1d + j];
            a1 += h * W1[i * H1d + j + 1];
        }
        a0 = (a0 - MU1[j]) * RS1[j] + BE1[j];             a0 = a0 > 0.0 ? a0 : 0.0;
        a1 = (a1 - MU1[j + 1]) * RS1[j + 1] + BE1[j + 1]; a1 = a1 > 0.0 ? a1 : 0.0;
        o[(size_t)j * Md]       = (float)a0;
        o[(size_t)(j + 1) * Md] = (float)a1;
    }
}

// ---------------------------------------------------------------------------
// K2: f32 GEMM, 128x128 tile, 8x8 per thread, BK=32 x 4 steps (32 KB LDS
// -> 4 blocks/CU, 4 waves/SIMD). Per-output accumulation is k=0..127
// ascending with acc carried across k-tiles: bitwise-identical logits to the
// verified BK=64 kernel.
// ---------------------------------------------------------------------------
__global__ __launch_bounds__(256, 4) void k2_gemm(
    const float* __restrict__ h1T,
    const float* __restrict__ w2,
    float* __restrict__ logits)
{
    __shared__ float As[32][128];            // 16 KB
    __shared__ float Bs[32][128];            // 16 KB
    const int bx = blockIdx.x, b = blockIdx.y;
    const int mtile = bx & 63, stile = bx >> 6;   // mtile fast: same-A blocks on one XCD
    const int m0 = mtile * 128, s0 = stile * 128;
    const int t = threadIdx.x;
    const int tm = t & 15, tn = t >> 4;

    float acc[8][8] = {};

    for (int kt = 0; kt < 4; kt++) {
        const float* Ag = h1T + ((size_t)b * H1d + kt * 32) * Md + m0;
        const float* Bg = w2 + (size_t)(kt * 32) * Sd + s0;
        #pragma unroll
        for (int i = 0; i < 4; i++) {
            int idx = t + i * 256;
            int kk = idx >> 5, c = idx & 31;
            *(float4*)&As[kk][c * 4] = *(const float4*)&Ag[(size_t)kk * Md + c * 4];
            *(float4*)&Bs[kk][c * 4] = *(const float4*)&Bg[(size_t)kk * Sd + c * 4];
        }
        __syncthreads();

        #pragma unroll 8
        for (int k = 0; k < 32; k++) {
            float a_[8], b_[8];
            *(float4*)&a_[0] = *(const float4*)&As[k][tm * 4];
            *(float4*)&a_[4] = *(const float4*)&As[k][64 + tm * 4];
            *(float4*)&b_[0] = *(const float4*)&Bs[k][tn * 4];
            *(float4*)&b_[4] = *(const float4*)&Bs[k][64 + tn * 4];
            #pragma unroll
            for (int si = 0; si < 8; si++)
                #pragma unroll
                for (int mi = 0; mi < 8; mi++)
                    acc[si][mi] += b_[si] * a_[mi];
        }
        __syncthreads();
    }

    #pragma unroll
    for (int si = 0; si < 8; si++) {
        int s = s0 + (si >> 2) * 64 + tn * 4 + (si & 3);
        float* row = logits + ((size_t)b * Sd + s) * Md + m0;
        *(float4*)&row[tm * 4]      = make_float4(acc[si][0], acc[si][1], acc[si][2], acc[si][3]);
        *(float4*)&row[64 + tm * 4] = make_float4(acc[si][4], acc[si][5], acc[si][6], acc[si][7]);
    }
}

// ---------------------------------------------------------------------------
// K3 (fused): selection + one-hot + gather, one block per (b,s) row.
// REVERTED to the round-7-verified version: ranking domain = f32
// Q = sigmoid(logit) via libm expf (matches the reference's f32 comparison
// domain INCLUDING its tie structure — raw-logit ranking broke ties
// differently where f32 sigmoid collapses distinct logits to equal Q).
// Threshold filter + rank-count; guard falls back to iterative extraction.
// ---------------------------------------------------------------------------
__global__ __launch_bounds__(256) void k3_fused(
    float* __restrict__ logits,              // row r read, then overwritten with Qg
    const float* __restrict__ gumbel,
    const float* __restrict__ coord,
    const float* __restrict__ feat,
    float* __restrict__ out)
{
    const int r = blockIdx.x;                // 0..4095
    const int b = r >> 10;
    const int t = threadIdx.x;
    const int lane = t & 63, wav = t >> 6;
    const float4* L4 = (const float4*)(logits + (size_t)r * Md);
    const float4* G4 = (const float4*)(gumbel + (size_t)r * Md);

    __shared__ unsigned long long wred[2][4];
    __shared__ unsigned long long ck[CAP];
    __shared__ unsigned swT[4];
    __shared__ int cnt;
    __shared__ int order[32];

    // ---- load + sigmoid + inline gumbel scan (float4, 16B/lane) ----
    unsigned uq[32];
    unsigned gbu = 0u; int gbm = 0;
    #pragma unroll
    for (int j = 0; j < 8; j++) {
        float4 v = L4[j * 256 + t];
        float4 g = G4[j * 256 + t];
        #pragma unroll
        for (int c = 0; c < 4; c++) {
            float x = ((const float*)&v)[c];
            float q = 1.0f / (1.0f + expf(-x));
            uq[j * 4 + c] = f2u(q);          // q>0 -> top bit set; 0 is a safe sentinel
            unsigned us = f2u(q + ((const float*)&g)[c]);
            if (us > gbu) { gbu = us; gbm = j * 1024 + t * 4 + c; }
        }
    }

    // ---- gumbel argmax reduce (first max -> smallest m via inverted-index key) ----
    {
        unsigned long long key = ((unsigned long long)gbu << 32) | (unsigned)(Md - 1 - gbm);
        #pragma unroll
        for (int o = 32; o > 0; o >>= 1) {
            unsigned long long other = __shfl_down(key, o);
            if (other > key) key = other;
        }
        if (lane == 0) wred[0][wav] = key;
    }
    if (t == 0) cnt = 0;
    __syncthreads();                         // B1: wred[0], cnt
    unsigned long long gbest = wred[0][0];
    if (wred[0][1] > gbest) gbest = wred[0][1];
    if (wred[0][2] > gbest) gbest = wred[0][2];
    if (wred[0][3] > gbest) gbest = wred[0][3];
    const int am = Md - 1 - (int)(gbest & 0xFFFFFFFFull);

    // ---- per-thread max, wave bitonic sort of 64 lane-maxima -> threshold T ----
    unsigned pm = 0u;
    #pragma unroll
    for (int i = 0; i < 32; i++) pm = max(pm, uq[i]);
    unsigned v = pm;
    #pragma unroll
    for (int k = 2; k <= 64; k <<= 1) {
        #pragma unroll
        for (int j = k >> 1; j > 0; j >>= 1) {
            unsigned o = __shfl_xor(v, j);
            bool up = ((lane & k) == 0);
            bool lower = ((lane & j) == 0);
            unsigned mn = min(v, o), mx = max(v, o);
            v = (lower == up) ? mn : mx;     // ascending by lane after final pass
        }
    }
    unsigned tw = __shfl(v, 32);             // asc pos 32 = 32nd largest of the wave
    if (lane == 0) swT[wav] = tw;
    __syncthreads();                         // B2: swT
    const unsigned T = max(max(swT[0], swT[1]), max(swT[2], swT[3]));

    // ---- collect candidates >= T ----
    #pragma unroll
    for (int i = 0; i < 32; i++) {
        if (uq[i] >= T) {
            int pos = atomicAdd(&cnt, 1);
            if (pos < CAP) {
                int m = (i >> 2) * 1024 + t * 4 + (i & 3);
                ck[pos] = ((unsigned long long)uq[i] << 32) | (unsigned)(Md - 1 - m);
            }
        }
    }
    __syncthreads();                         // B3: ck, cnt
    const int n = cnt;

    if (n >= 32 && n <= CAP) {
        // ---- fast path: O(n^2) rank-count ----
        for (int j2 = t; j2 < n; j2 += 256) {
            unsigned long long mine = ck[j2];
            int rk = 0;
            for (int i2 = 0; i2 < n; i2++) rk += (ck[i2] > mine) ? 1 : 0;
            if (rk < 32) order[rk] = Md - 1 - (int)(mine & 0xFFFFFFFFull);
        }
    } else {
        // ---- fallback: verified iterative extraction ----
        for (int round = 0; round < 32; round++) {
            unsigned bu = 0u; int bi = 0;
            #pragma unroll
            for (int i = 0; i < 32; i++)
                if (uq[i] > bu) { bu = uq[i]; bi = i; }
            int bm = (bi >> 2) * 1024 + t * 4 + (bi & 3);
            unsigned long long key =
                ((unsigned long long)bu << 32) | (unsigned)(Md - 1 - bm);
            #pragma unroll
            for (int o = 32; o > 0; o >>= 1) {
                unsigned long long other = __shfl_down(key, o);
                if (other > key) key = other;
            }
            const int p = round & 1;
            if (lane == 0) wred[p][wav] = key;
            __syncthreads();
            unsigned long long best = wred[p][0];
            if (wred[p][1] > best) best = wred[p][1];
            if (wred[p][2] > best) best = wred[p][2];
            if (wred[p][3] > best) best = wred[p][3];
            const int m_win = Md - 1 - (int)(best & 0xFFFFFFFFull);
            if (((m_win >> 2) & 255) == t)
                uq[(m_win >> 10) * 4 + (m_win & 3)] = 0u;
            if (t == 0) order[round] = m_win;
        }
    }
    __syncthreads();                         // B4: order[] visible

    // ---- outputs ----
    // Qg one-hot (overwrites this block's own logits row)
    {
        const int q4 = am >> 2;
        float4* row = (float4*)(logits + (size_t)r * Md);
        #pragma unroll
        for (int i = 0; i < 8; i++) {
            int idx = i * 256 + t;
            float4 vv = make_float4(0.f, 0.f, 0.f, 0.f);
            if (idx == q4) ((float*)&vv)[am & 3] = 1.0f;
            row[idx] = vv;
        }
    }
    if (t < 3)
        out[OFF_SP + (size_t)r * 3 + t] = coord[((size_t)b * Md + am) * 3 + t];
    if (t >= 32 && t < 128) {
        int e = t - 32;                      // 0..95
        int nn = e / 3, c = e - nn * 3;
        out[OFF_GP + (size_t)r * 96 + e] = coord[((size_t)b * Md + order[nn]) * 3 + c];
    }
    const float4* F4  = (const float4*)feat;          // feat row = 16 float4
    float4* SF4 = (float4*)(out + OFF_SF);
    float4* GF4 = (float4*)(out + OFF_GF);
    if (t < 16) {
        float4 fv = F4[((size_t)b * Md + am) * 16 + t];
        SF4[(size_t)r * 16 + t]  = fv;       // sampled_feature
        GF4[(size_t)r * 512 + t] = fv;       // grouped_feature[.,.,0,:]
    }
    for (int e4 = 16 + t; e4 < 512; e4 += 256) {
        int nn = e4 >> 4, d4 = e4 & 15;
        GF4[(size_t)r * 512 + e4] = F4[((size_t)b * Md + order[nn]) * 16 + d4];
    }
}

// ---------------------------------------------------------------------------
extern "C" void kernel_launch(void* const* d_in, const int* in_sizes, int n_in,
                              void* d_out, int out_size, void* d_ws, size_t ws_size,
                              hipStream_t stream)
{
    (void)in_sizes; (void)n_in; (void)out_size; (void)d_ws; (void)ws_size;
    const float* coord = (const float*)d_in[0];
    const float* feat  = (const float*)d_in[1];
    const float* gum   = (const float*)d_in[2];
    const float* w0    = (const float*)d_in[3];
    const float* g0    = (const float*)d_in[4];
    const float* be0   = (const float*)d_in[5];
    const float* mu0   = (const float*)d_in[6];
    const float* va0   = (const float*)d_in[7];
    const float* w1    = (const float*)d_in[8];
    const float* g1    = (const float*)d_in[9];
    const float* be1   = (const float*)d_in[10];
    const float* mu1   = (const float*)d_in[11];
    const float* va1   = (const float*)d_in[12];
    const float* w2    = (const float*)d_in[13];

    float*  out    = (float*)d_out;
    float*  h1T    = out + OFF_GF;              // f32 h1T scratch (overwritten by k3 gather)
    float*  logits = out + OFF_QG;              // f32 logits -> Qg one-hot

    k1_mlp   <<<dim3(128),     dim3(256), 0, stream>>>(coord, w0, g0, be0, mu0, va0,
                                                       w1, g1, be1, mu1, va1, h1T);
    k2_gemm  <<<dim3(512, 4),  dim3(256), 0, stream>>>(h1T, w2, logits);
    k3_fused <<<dim3(4096),    dim3(256), 0, stream>>>(logits, gum, coord, feat, out);
}